// Round 10
// baseline (653.096 us; speedup 1.0000x reference)
//
#include <hip/hip_runtime.h>

#define NB    65536
#define ND    256
#define NK    1024
#define BM    64
#define BN    128
#define BDC   64
#define XS    68
#define WSTR  68
#define TAU      1e-2f   // pass-1 margin below which fixup re-decides
#define EPS_TIE  1e-4    // fp64 gap below which fp32 pipelines collapse -> lowest index
#define MAXFLAG  16384

// prep: fast w2 (pass-1 fp32) + exact fp64 w2; zero loss slots + flag counter.
__global__ __launch_bounds__(256) void prep_kernel(const float* __restrict__ W,
                                                   float* __restrict__ w2f,
                                                   double* __restrict__ w2d,
                                                   int* __restrict__ cnt,
                                                   float* __restrict__ out) {
    int wv   = threadIdx.x >> 6;
    int lane = threadIdx.x & 63;
    int code = blockIdx.x * 4 + wv;
    const float4 v = *reinterpret_cast<const float4*>(W + (size_t)code * ND + lane * 4);
    float  s  = v.x*v.x + v.y*v.y + v.z*v.z + v.w*v.w;
    double sd = (double)v.x*(double)v.x + (double)v.y*(double)v.y
              + (double)v.z*(double)v.z + (double)v.w*(double)v.w;
    #pragma unroll
    for (int m = 32; m >= 1; m >>= 1) { s += __shfl_xor(s, m, 64); sd += __shfl_xor(sd, m, 64); }
    if (lane == 0) { w2f[code] = s; w2d[code] = sd; }
    if (blockIdx.x == 0 && threadIdx.x == 0) {
        out[(size_t)NB * ND]     = 0.f;
        out[(size_t)NB * ND + 1] = 0.f;
        *cnt = 0;
    }
}

__global__ __launch_bounds__(256) void vq_kernel(const float* __restrict__ x,
                                                 const float* __restrict__ W,
                                                 const float* __restrict__ w2,
                                                 int* __restrict__ flag_cnt,
                                                 int* __restrict__ flag_list,
                                                 float* __restrict__ out) {
    __shared__ float xs[BM * XS];
    __shared__ float ws[BN * WSTR];
    __shared__ int   sidx[BM];
    __shared__ unsigned char sflg[BM];
    __shared__ float sred[4];

    const int tid  = threadIdx.x;
    const int row0 = blockIdx.x * BM;
    const int rr   = tid >> 4;   // row group: rows rr + 16*i
    const int cr   = tid & 15;   // code group: codes cr + 16*j

    float best[4], best2[4];
    int   bidx[4];
    #pragma unroll
    for (int i = 0; i < 4; ++i) { best[i] = 3.402823466e38f; best2[i] = 3.402823466e38f; bidx[i] = 0; }

    for (int ct = 0; ct < NK / BN; ++ct) {
        float acc[4][8];
        #pragma unroll
        for (int i = 0; i < 4; ++i)
            #pragma unroll
            for (int j = 0; j < 8; ++j) acc[i][j] = 0.f;

        for (int dt = 0; dt < ND / BDC; ++dt) {
            __syncthreads();
            #pragma unroll
            for (int it = 0; it < 4; ++it) {
                int c = tid + it * 256;
                int row = c >> 4, d4 = c & 15;
                float4 v = *reinterpret_cast<const float4*>(
                    x + (size_t)(row0 + row) * ND + dt * BDC + d4 * 4);
                *reinterpret_cast<float4*>(&xs[row * XS + d4 * 4]) = v;
            }
            #pragma unroll
            for (int it = 0; it < 8; ++it) {
                int c = tid + it * 256;
                int code = c >> 4, d4 = c & 15;
                float4 v = *reinterpret_cast<const float4*>(
                    W + (size_t)(ct * BN + code) * ND + dt * BDC + d4 * 4);
                *reinterpret_cast<float4*>(&ws[code * WSTR + d4 * 4]) = v;
            }
            __syncthreads();

            for (int d4 = 0; d4 < 16; ++d4) {
                float4 a[4], b[8];
                #pragma unroll
                for (int i = 0; i < 4; ++i)
                    a[i] = *reinterpret_cast<const float4*>(&xs[(rr + 16*i) * XS + d4 * 4]);
                #pragma unroll
                for (int j = 0; j < 8; ++j)
                    b[j] = *reinterpret_cast<const float4*>(&ws[(cr + 16*j) * WSTR + d4 * 4]);
                #pragma unroll
                for (int i = 0; i < 4; ++i)
                    #pragma unroll
                    for (int j = 0; j < 8; ++j) {
                        acc[i][j] = fmaf(a[i].x, b[j].x, acc[i][j]);
                        acc[i][j] = fmaf(a[i].y, b[j].y, acc[i][j]);
                        acc[i][j] = fmaf(a[i].z, b[j].z, acc[i][j]);
                        acc[i][j] = fmaf(a[i].w, b[j].w, acc[i][j]);
                    }
            }
        }

        // score = w2 - 2*dot  (x2 dropped: per-row constant, argmin/margin-invariant)
        #pragma unroll
        for (int j = 0; j < 8; ++j) {
            int code = ct * BN + cr + 16 * j;
            float w2v = w2[code];
            #pragma unroll
            for (int i = 0; i < 4; ++i) {
                float s = fmaf(-2.f, acc[i][j], w2v);
                if (s < best[i])       { best2[i] = best[i]; best[i] = s; bidx[i] = code; }
                else if (s < best2[i]) { best2[i] = s; }
            }
        }
    }

    // top-2 argmin reduce across the 16 lanes sharing each row group
    #pragma unroll
    for (int m = 1; m < 16; m <<= 1) {
        #pragma unroll
        for (int i = 0; i < 4; ++i) {
            float ob  = __shfl_xor(best[i],  m, 64);
            float ob2 = __shfl_xor(best2[i], m, 64);
            int   oi  = __shfl_xor(bidx[i],  m, 64);
            float nb2 = fminf(fmaxf(best[i], ob), fminf(best2[i], ob2));
            if (ob < best[i] || (ob == best[i] && oi < bidx[i])) { best[i] = ob; bidx[i] = oi; }
            best2[i] = nb2;
        }
    }
    if (cr == 0) {
        #pragma unroll
        for (int i = 0; i < 4; ++i) {
            int r = rr + 16 * i;
            sidx[r] = bidx[i];
            bool fl = (best2[i] - best[i]) < TAU;
            if (fl) {
                int p = atomicAdd(flag_cnt, 1);
                if (p < MAXFLAG) flag_list[p] = row0 + r;
                else fl = false;
            }
            sflg[r] = fl ? 1 : 0;
        }
    }
    __syncthreads();

    const int lane = tid & 63;
    const int wv   = tid >> 6;
    float lsum = 0.f;
    for (int rg = 0; rg < 16; ++rg) {
        int r = rg * 4 + wv;
        int code = sidx[r];
        float4 q  = *reinterpret_cast<const float4*>(W + (size_t)code * ND + lane * 4);
        float4 xv = *reinterpret_cast<const float4*>(x + (size_t)(row0 + r) * ND + lane * 4);
        *reinterpret_cast<float4*>(out + (size_t)(row0 + r) * ND + lane * 4) = q;
        if (!sflg[r]) {
            float dx = q.x - xv.x, dy = q.y - xv.y, dz = q.z - xv.z, dw = q.w - xv.w;
            lsum += dx*dx + dy*dy + dz*dz + dw*dw;
        }
    }
    if (tid < BM) out[(size_t)NB * ND + 2 + row0 + tid] = (float)sidx[tid];

    #pragma unroll
    for (int m = 32; m >= 1; m >>= 1) lsum += __shfl_xor(lsum, m, 64);
    if (lane == 0) sred[wv] = lsum;
    __syncthreads();
    if (tid == 0) {
        float t = (sred[0] + sred[1] + sred[2] + sred[3]) * (1.f / ((float)NB * (float)ND));
        atomicAdd(&out[(size_t)NB * ND], t);
        atomicAdd(&out[(size_t)NB * ND + 1], t);
    }
}

// Flagged rows: fp64 exact top-2; if gap < EPS_TIE the pair collapses to equality
// in any fp32 pipeline -> np.argmin takes the LOWEST index. Else fp64 truth.
__global__ __launch_bounds__(256) void fixup_tie(const float* __restrict__ x,
                                                 const float* __restrict__ W,
                                                 const double* __restrict__ w2d,
                                                 const int* __restrict__ cnt,
                                                 const int* __restrict__ list,
                                                 float* __restrict__ out) {
    __shared__ float  xs[ND];
    __shared__ double xd[ND];
    __shared__ double rb1[4], rb2[4];
    __shared__ int    ri1[4], ri2[4];
    __shared__ int    schoice;
    __shared__ float  sl[4];

    int n = *cnt; if (n > MAXFLAG) n = MAXFLAG;
    const int tid  = threadIdx.x;
    const int wv   = tid >> 6;
    const int lane = tid & 63;

    for (int f = blockIdx.x; f < n; f += gridDim.x) {
        const int row = list[f];
        __syncthreads();   // protect shared reuse across f-iterations
        float xv = x[(size_t)row * ND + tid];
        xs[tid] = xv; xd[tid] = (double)xv;
        __syncthreads();

        // fp64 top-2 over all codes
        double b1 = 1e300, b2 = 1e300; int i1 = 0, i2 = 0;
        #pragma unroll
        for (int k = 0; k < 4; ++k) {
            const int c = tid + k * 256;
            const float* wr = W + (size_t)c * ND;
            double dot = 0.0;
            for (int d = 0; d < ND; d += 4) {
                dot += (double)wr[d]   * xd[d]   + (double)wr[d+1] * xd[d+1]
                     + (double)wr[d+2] * xd[d+2] + (double)wr[d+3] * xd[d+3];
            }
            double s = w2d[c] - 2.0 * dot;
            if (s < b1 || (s == b1 && c < i1)) { b2 = b1; i2 = i1; b1 = s; i1 = c; }
            else if (s < b2 || (s == b2 && c < i2)) { b2 = s; i2 = c; }
        }
        #pragma unroll
        for (int m = 1; m < 64; m <<= 1) {
            double ob1 = __shfl_xor(b1, m, 64), ob2 = __shfl_xor(b2, m, 64);
            int    oi1 = __shfl_xor(i1, m, 64), oi2 = __shfl_xor(i2, m, 64);
            if (ob1 < b1 || (ob1 == b1 && oi1 < i1)) {
                if (b1 < ob2 || (b1 == ob2 && i1 < oi2)) { b2 = b1; i2 = i1; }
                else                                     { b2 = ob2; i2 = oi2; }
                b1 = ob1; i1 = oi1;
            } else if (ob1 < b2 || (ob1 == b2 && oi1 < i2)) { b2 = ob1; i2 = oi1; }
        }
        if (lane == 0) { rb1[wv] = b1; ri1[wv] = i1; rb2[wv] = b2; ri2[wv] = i2; }
        __syncthreads();
        if (tid == 0) {
            double B1 = rb1[0], B2 = rb2[0]; int I1 = ri1[0], I2 = ri2[0];
            for (int w = 1; w < 4; ++w) {
                double ob1 = rb1[w], ob2 = rb2[w]; int oi1 = ri1[w], oi2 = ri2[w];
                if (ob1 < B1 || (ob1 == B1 && oi1 < I1)) {
                    if (B1 < ob2 || (B1 == ob2 && I1 < oi2)) { B2 = B1; I2 = I1; }
                    else                                     { B2 = ob2; I2 = oi2; }
                    B1 = ob1; I1 = oi1;
                } else if (ob1 < B2 || (ob1 == B2 && oi1 < I2)) { B2 = ob1; I2 = oi1; }
            }
            // deep-tie rule: fp32 pipelines collapse the pair -> first index wins
            schoice = ((B2 - B1) < EPS_TIE) ? min(I1, I2) : I1;
        }
        __syncthreads();
        const int c = schoice;
        float q = W[(size_t)c * ND + tid];
        out[(size_t)row * ND + tid] = q;
        float dd = q - xs[tid];
        float ls = dd * dd;
        #pragma unroll
        for (int m = 32; m >= 1; m >>= 1) ls += __shfl_xor(ls, m, 64);
        if (lane == 0) sl[wv] = ls;
        __syncthreads();
        if (tid == 0) {
            float t = (sl[0] + sl[1] + sl[2] + sl[3]) * (1.f / ((float)NB * (float)ND));
            atomicAdd(&out[(size_t)NB * ND], t);
            atomicAdd(&out[(size_t)NB * ND + 1], t);
            out[(size_t)NB * ND + 2 + row] = (float)c;
        }
    }
}

extern "C" void kernel_launch(void* const* d_in, const int* in_sizes, int n_in,
                              void* d_out, int out_size, void* d_ws, size_t ws_size,
                              hipStream_t stream) {
    const float* x = (const float*)d_in[0];
    const float* W = (const float*)d_in[1];
    float* out = (float*)d_out;

    float*  w2f  = (float*)d_ws;                      // 4 KB
    double* w2d  = (double*)((char*)d_ws + 4096);     // 8 KB
    int*    cnt  = (int*)((char*)d_ws + 12288);
    int*    list = (int*)((char*)d_ws + 12352);       // MAXFLAG ints

    prep_kernel<<<NK / 4, 256, 0, stream>>>(W, w2f, w2d, cnt, out);
    vq_kernel<<<NB / BM, 256, 0, stream>>>(x, W, w2f, cnt, list, out);
    fixup_tie<<<256, 256, 0, stream>>>(x, W, w2d, cnt, list, out);
}